// Round 4
// baseline (53.233 us; speedup 1.0000x reference)
//
#include <hip/hip_runtime.h>

typedef _Float16 f16x8 __attribute__((ext_vector_type(8)));
typedef float f32x4 __attribute__((ext_vector_type(4)));

#define MROWS 65536
#define BM 32
#define NBLK (MROWS / BM)  // 2048

// ---- d_ws byte offsets ----
#define B1F_OFF 0u       // GEMM1 B frags: [4kt][16nt][64lane][8] f16 = 65536 B
#define B2F_OFF 65536u   // GEMM2 B frags: [8kt][16nt][64lane][8] f16 = 131072 B
#define TP_OFF 196608u   // phone_table @ W1[64:192], PERMUTED cols: [100][256] f32
#define TM_OFF 299008u   // midi_table @ W1[192:256], PERMUTED cols: [128][256] f32
#define BC_OFF 430080u   // fused bias, PERMUTED: [256] f32
#define WFD_OFF 431104u  // fused f0/dur weights (unpermuted): [64][256] f32
#define LNG_OFF 496640u  // ln_g PERMUTED [256] f32
#define LNB_OFF 497664u  // ln_b PERMUTED [256] f32
#define B2P_OFF 498688u  // proj_b2 PERMUTED [256] f32
// total 499712 B

// Fragment k-slot mapping used consistently for ALL A and B fragments:
//   k = kt*32 + 4*(lane>>4) + (e&3) + 16*(e>>2)
// (A: row = lane&15; B: col = lane&15. C/D: col = lane&15, row = (lane>>4)*4 + reg)

// Gather-table column permutation: logical col n = wc*64 + j*16 + c  is stored at
// wc*64 + c*4 + j, so one lane's 4 j-values are one contiguous float4.
__device__ __forceinline__ int gperm(int n) {
  return (n & ~63) | ((n & 15) << 2) | ((n >> 4) & 3);
}

// LDS A-frag swizzle: 16B-granule bijection, XORs addr bits [4:6] with X bits [3:5].
// Pack-phase scattered 8B writes ~conflict-free (measured 3.15M -> 0), b128 reads clean.
__device__ __forceinline__ unsigned afoff(unsigned X) {
  return (X * 16u) ^ ((X & 0x38u) << 1);
}

__global__ __launch_bounds__(256) void prep_tables(
    const float* __restrict__ f0_w2, const float* __restrict__ f0_b2,
    const float* __restrict__ ptab, const float* __restrict__ mtab,
    const float* __restrict__ dur_w2, const float* __restrict__ dur_b2,
    const float* __restrict__ W1, const float* __restrict__ pb1,
    const float* __restrict__ ln_g, const float* __restrict__ ln_b,
    const float* __restrict__ pb2, float* __restrict__ wsf) {
  const int r = blockIdx.x, n = threadIdx.x;
  if (r < 64) {  // Wfd row r (unpermuted: feeds prep_frags)
    float s = 0.f;
    if (r < 32) {
      for (int j = 0; j < 64; ++j) s = fmaf(f0_w2[r * 64 + j], W1[j * 256 + n], s);
    } else {
      for (int j = 0; j < 64; ++j) s = fmaf(dur_w2[(r - 32) * 64 + j], W1[(256 + j) * 256 + n], s);
    }
    wsf[WFD_OFF / 4 + r * 256 + n] = s;
  } else if (r < 164) {  // Tp row (permuted cols)
    const int p = r - 64;
    float s = 0.f;
    for (int j = 0; j < 128; ++j) s = fmaf(ptab[p * 128 + j], W1[(64 + j) * 256 + n], s);
    wsf[TP_OFF / 4 + p * 256 + gperm(n)] = s;
  } else if (r < 292) {  // Tm row (permuted cols)
    const int m = r - 164;
    float s = 0.f;
    for (int j = 0; j < 64; ++j) s = fmaf(mtab[m * 64 + j], W1[(192 + j) * 256 + n], s);
    wsf[TM_OFF / 4 + m * 256 + gperm(n)] = s;
  } else if (r == 292) {  // fused bias (permuted)
    float s = pb1[n];
    for (int j = 0; j < 64; ++j) {
      s = fmaf(f0_b2[j], W1[j * 256 + n], s);
      s = fmaf(dur_b2[j], W1[(256 + j) * 256 + n], s);
    }
    wsf[BC_OFF / 4 + gperm(n)] = s;
  } else {  // permuted copies of ln_g / ln_b / proj_b2
    wsf[LNG_OFF / 4 + gperm(n)] = ln_g[n];
    wsf[LNB_OFF / 4 + gperm(n)] = ln_b[n];
    wsf[B2P_OFF / 4 + gperm(n)] = pb2[n];
  }
}

__global__ __launch_bounds__(64) void prep_frags(const float* __restrict__ W2, char* __restrict__ ws) {
  const float* Wfd = (const float*)(ws + WFD_OFF);
  const int t = blockIdx.x;
  const int l = threadIdx.x;
  const int qq = l >> 4, c = l & 15;
  if (t < 64) {  // B1: [Wfd; Wfd] duplicated over K=128 (A is hi/lo split)
    const int kt = t >> 4, nt = t & 15;
    f16x8 v;
#pragma unroll
    for (int e = 0; e < 8; ++e) {
      const int k = kt * 32 + 4 * qq + (e & 3) + 16 * (e >> 2);
      v[e] = (_Float16)Wfd[(k & 63) * 256 + nt * 16 + c];
    }
    *(f16x8*)(ws + B1F_OFF + (unsigned)((kt * 16 + nt) * 64 + l) * 16u) = v;
  } else {  // B2 = proj_w2
    const int t2 = t - 64;
    const int kt = t2 >> 4, nt = t2 & 15;
    f16x8 v;
#pragma unroll
    for (int e = 0; e < 8; ++e) {
      const int k = kt * 32 + 4 * qq + (e & 3) + 16 * (e >> 2);
      v[e] = (_Float16)W2[k * 256 + nt * 16 + c];
    }
    *(f16x8*)(ws + B2F_OFF + (unsigned)((kt * 16 + nt) * 64 + l) * 16u) = v;
  }
}

__global__ __launch_bounds__(256, 2) void cond_enc_main(
    const float* __restrict__ f0g, const int* __restrict__ phone,
    const float* __restrict__ durg, const int* __restrict__ midi,
    const float* __restrict__ f0_w1, const float* __restrict__ f0_b1,
    const float* __restrict__ dur_w1, const float* __restrict__ dur_b1,
    const char* __restrict__ ws, float* __restrict__ out) {
  // LDS: [0,16K) A2 frags (swizzled via afoff); then LN partials [32][12] f32
  __shared__ __align__(16) unsigned char smem[16384 + 1536];
  unsigned char* Afrag = smem;
  float* partials = (float*)(smem + 16384);

  const int tid = threadIdx.x;
  const int l = tid & 63;
  const int wc = tid >> 6;  // wave 0..3 = column group (64 cols each)
  const int q = l >> 4;     // 0..3
  const int c = l & 15;     // 0..15
  const int b = blockIdx.x;

  const float* Tp = (const float*)(ws + TP_OFF);
  const float* Tm = (const float*)(ws + TM_OFF);

  // ---- gather indices straight into registers (no LDS, no barrier) ----
  int phv[2][4], mdv[2][4];
#pragma unroll
  for (int i = 0; i < 2; ++i)
#pragma unroll
    for (int r = 0; r < 4; ++r) {
      const int grow = b * BM + i * 16 + q * 4 + r;
      phv[i][r] = phone[grow];
      mdv[i][r] = midi[grow];
    }

  // ---- Phase 0: A1 fragments computed fully in registers ----
  // a = relu(x*w1+b1), hi/lo f16 split. kt0=f0.hi kt1=dur.hi kt2=f0.lo kt3=dur.lo
  f16x8 a1[2][4];
#pragma unroll
  for (int i = 0; i < 2; ++i) {
    const float xf = f0g[b * BM + i * 16 + c];
    const float xd = durg[b * BM + i * 16 + c];
#pragma unroll
    for (int kh = 0; kh < 2; ++kh) {
      f16x8 hi, lo;
#pragma unroll
      for (int e = 0; e < 8; ++e) {
        const int ki = 4 * q + (e & 3) + 16 * (e >> 2);  // 0..31
        const float wv = kh ? dur_w1[ki] : f0_w1[ki];
        const float bv = kh ? dur_b1[ki] : f0_b1[ki];
        const float x = kh ? xd : xf;
        const float a = fmaxf(fmaf(x, wv, bv), 0.f);
        const _Float16 h = (_Float16)a;
        hi[e] = h;
        lo[e] = (_Float16)(a - (float)h);
      }
      a1[i][kh] = hi;
      a1[i][kh + 2] = lo;
    }
  }

  // ---- Phase 1: GEMM1  h = [a_hi|a_lo] @ [Wfd;Wfd]  (K=128) ----
  const f32x4 zero4 = {0.f, 0.f, 0.f, 0.f};
  f32x4 acc[2][4];
#pragma unroll
  for (int i = 0; i < 2; ++i)
#pragma unroll
    for (int j = 0; j < 4; ++j) acc[i][j] = zero4;
  {
    const f16x8* B1p = (const f16x8*)(ws + B1F_OFF);
#pragma unroll
    for (int kt = 0; kt < 4; ++kt) {
      f16x8 b4[4];
#pragma unroll
      for (int j = 0; j < 4; ++j) b4[j] = B1p[(kt * 16 + wc * 4 + j) * 64 + l];
#pragma unroll
      for (int i = 0; i < 2; ++i)
#pragma unroll
        for (int j = 0; j < 4; ++j)
          acc[i][j] = __builtin_amdgcn_mfma_f32_16x16x32_f16(a1[i][kt], b4[j], acc[i][j], 0, 0, 0);
    }
  }

  // ---- Epilogue: += bias + Tp[phone] + Tm[midi] (permuted float4 gathers) ----
  const f32x4 bc4 = *(const f32x4*)((const float*)(ws + BC_OFF) + wc * 64 + c * 4);
  float psum[2][4], psq[2][4];
#pragma unroll
  for (int i = 0; i < 2; ++i) {
#pragma unroll
    for (int r = 0; r < 4; ++r) {
      const f32x4 tp4 = *(const f32x4*)(Tp + phv[i][r] * 256 + wc * 64 + c * 4);
      const f32x4 tm4 = *(const f32x4*)(Tm + mdv[i][r] * 256 + wc * 64 + c * 4);
      float s = 0.f, ss = 0.f;
#pragma unroll
      for (int j = 0; j < 4; ++j) {
        float v = acc[i][j][r] + bc4[j] + tp4[j] + tm4[j];
        acc[i][j][r] = v;
        s += v;
        ss = fmaf(v, v, ss);
      }
      psum[i][r] = s;
      psq[i][r] = ss;
    }
  }
#pragma unroll
  for (int i = 0; i < 2; ++i)
#pragma unroll
    for (int r = 0; r < 4; ++r) {
      float s = psum[i][r], ss = psq[i][r];
#pragma unroll
      for (int m = 1; m < 16; m <<= 1) {  // reduce across the 16 col-lanes
        s += __shfl_xor(s, m, 64);
        ss += __shfl_xor(ss, m, 64);
      }
      psum[i][r] = s;
      psq[i][r] = ss;
    }
  if (c == 0) {
#pragma unroll
    for (int i = 0; i < 2; ++i)
#pragma unroll
      for (int r = 0; r < 4; ++r) {
        const int row = i * 16 + q * 4 + r;
        partials[row * 12 + wc * 2 + 0] = psum[i][r];
        partials[row * 12 + wc * 2 + 1] = psq[i][r];
      }
  }
  __syncthreads();

  // ---- LN stats (redundant per lane; partials row is two aligned b128 reads)
  //      + normalize + ReLU + pack into GEMM2 A-fragments ----
  const f32x4 g4 = *(const f32x4*)((const float*)(ws + LNG_OFF) + wc * 64 + c * 4);
  const f32x4 lb4 = *(const f32x4*)((const float*)(ws + LNB_OFF) + wc * 64 + c * 4);
  const int jj = c >> 2;  // col-quad -> target lane's (l'>>4)
  const int tq = c & 3;
#pragma unroll
  for (int i = 0; i < 2; ++i) {
#pragma unroll
    for (int r = 0; r < 4; ++r) {
      const int row = i * 16 + q * 4 + r;
      const f32x4 pa = *(const f32x4*)(partials + row * 12);
      const f32x4 pb = *(const f32x4*)(partials + row * 12 + 4);
      const float s = pa[0] + pa[2] + pb[0] + pb[2];
      const float ss = pa[1] + pa[3] + pb[1] + pb[3];
      const float mu = s * (1.f / 256.f);
      const float var = fmaxf(ss * (1.f / 256.f) - mu * mu, 0.f);
      const float rstd = rsqrtf(var + 1e-5f);
#pragma unroll
      for (int j = 0; j < 4; ++j) {
        float v = fmaf((acc[i][j][r] - mu) * rstd, g4[j], lb4[j]);
        v = fmaxf(v, 0.f);
        const unsigned short u = __builtin_bit_cast(unsigned short, (_Float16)v);
        const unsigned int su = (unsigned int)__shfl_xor((int)u, 1, 64);
        const unsigned int p = (unsigned int)u | (su << 16);
        const unsigned int p2 = (unsigned int)__shfl_xor((int)p, 2, 64);
        if (tq == 0) {  // lane holds 4 consecutive cols packed: write 8B into A2 slot
          const int lp = q * 4 + r + 16 * jj;  // A-frag lane: (row&15) + 16*q'
          const int kt = wc * 2 + (j >> 1);    // k-tile 0..7 (k = col)
          const unsigned X = (unsigned)((kt * 2 + i) * 64 + lp);
          unsigned int* dst = (unsigned int*)(Afrag + afoff(X) + (unsigned)(j & 1) * 8u);
          dst[0] = p;
          dst[1] = p2;
        }
      }
    }
  }
  __syncthreads();

  // ---- Phase 2: GEMM2  out = relu(LN(h)) @ W2 + b2  (K=256), acc reused ----
#pragma unroll
  for (int i = 0; i < 2; ++i)
#pragma unroll
    for (int j = 0; j < 4; ++j) acc[i][j] = zero4;
  {
    const f16x8* B2p = (const f16x8*)(ws + B2F_OFF);
#pragma unroll
    for (int kt = 0; kt < 8; ++kt) {
      f16x8 a4[2], b4[4];
#pragma unroll
      for (int i = 0; i < 2; ++i)
        a4[i] = *(const f16x8*)(Afrag + afoff((unsigned)((kt * 2 + i) * 64 + l)));
#pragma unroll
      for (int j = 0; j < 4; ++j) b4[j] = B2p[(kt * 16 + wc * 4 + j) * 64 + l];
#pragma unroll
      for (int i = 0; i < 2; ++i)
#pragma unroll
        for (int j = 0; j < 4; ++j)
          acc[i][j] = __builtin_amdgcn_mfma_f32_16x16x32_f16(a4[i], b4[j], acc[i][j], 0, 0, 0);
    }
  }
  const f32x4 b24 = *(const f32x4*)((const float*)(ws + B2P_OFF) + wc * 64 + c * 4);
#pragma unroll
  for (int i = 0; i < 2; ++i)
#pragma unroll
    for (int j = 0; j < 4; ++j)
#pragma unroll
      for (int r = 0; r < 4; ++r) {
        const int grow = b * BM + i * 16 + q * 4 + r;
        const int col = wc * 64 + j * 16 + c;
        out[grow * 256 + col] = acc[i][j][r] + b24[j];
      }
}

extern "C" void kernel_launch(void* const* d_in, const int* in_sizes, int n_in,
                              void* d_out, int out_size, void* d_ws, size_t ws_size,
                              hipStream_t stream) {
  (void)in_sizes; (void)n_in; (void)out_size; (void)ws_size;
  const float* f0 = (const float*)d_in[0];
  const int* phone = (const int*)d_in[1];
  const float* dur = (const float*)d_in[2];
  const int* midi = (const int*)d_in[3];
  const float* f0_w1 = (const float*)d_in[4];
  const float* f0_b1 = (const float*)d_in[5];
  const float* f0_w2 = (const float*)d_in[6];
  const float* f0_b2 = (const float*)d_in[7];
  const float* ptab = (const float*)d_in[8];
  const float* mtab = (const float*)d_in[9];
  const float* dur_w1 = (const float*)d_in[10];
  const float* dur_b1 = (const float*)d_in[11];
  const float* dur_w2 = (const float*)d_in[12];
  const float* dur_b2 = (const float*)d_in[13];
  const float* W1 = (const float*)d_in[14];
  const float* pb1 = (const float*)d_in[15];
  const float* ln_g = (const float*)d_in[16];
  const float* ln_b = (const float*)d_in[17];
  const float* W2 = (const float*)d_in[18];
  const float* pb2 = (const float*)d_in[19];
  char* ws = (char*)d_ws;
  float* out = (float*)d_out;

  prep_tables<<<294, 256, 0, stream>>>(f0_w2, f0_b2, ptab, mtab, dur_w2, dur_b2, W1, pb1,
                                       ln_g, ln_b, pb2, (float*)ws);
  prep_frags<<<192, 64, 0, stream>>>(W2, ws);
  cond_enc_main<<<NBLK, 256, 0, stream>>>(f0, phone, dur, midi, f0_w1, f0_b1, dur_w1, dur_b1,
                                          ws, out);
}

// Round 5
// 45.810 us; speedup vs baseline: 1.1620x; 1.1620x over previous
//
#include <hip/hip_runtime.h>

typedef _Float16 f16x8 __attribute__((ext_vector_type(8)));
typedef float f32x4 __attribute__((ext_vector_type(4)));
typedef unsigned int u32x2 __attribute__((ext_vector_type(2)));

#define MROWS 65536
#define BM 32
#define NBLK (MROWS / BM)  // 2048

// ---- d_ws byte offsets ----
#define B1F_OFF 0u       // GEMM1 B frags: [4kt][16nt][64lane][8] f16 = 65536 B
#define B2F_OFF 65536u   // GEMM2 B frags: [8kt][16nt][64lane][8] f16 = 131072 B
#define TP_OFF 196608u   // phone_table @ W1[64:192]: [100][256] f32 (plain layout)
#define TM_OFF 299008u   // midi_table @ W1[192:256]: [128][256] f32 (plain layout)
#define BC_OFF 430080u   // fused bias: [256] f32 (plain layout)
#define WFD_OFF 431104u  // fused f0/dur weights: [64][256] f32
// total 496640 B

// Fragment k-slot mapping (all A and B fragments):
//   k = kt*32 + 4*(lane>>4) + (e&3) + 16*(e>>2)
// B fragments use a PERMUTED column layout: tile nt, lane c holds logical
// column (nt>>2)*64 + c*4 + (nt&3).  In-wave (nt = wc*4 + j) each lane's four
// j-values are 4 CONSECUTIVE logical columns wc*64 + c*4 + {0..3}.  This makes
// table reads / LN params / bias / output stores plain float4, and the
// LN->GEMM2 repack a pure per-lane 8B LDS write (no shuffles).
// C/D: col_tile = lane&15 -> logical col via same permutation; row = (lane>>4)*4 + reg.

// LDS A-frag swizzle: 16B-granule bijection, XORs addr bits [4:6] with X bits [3:5].
__device__ __forceinline__ unsigned afoff(unsigned X) {
  return (X * 16u) ^ ((X & 0x38u) << 1);
}

__global__ __launch_bounds__(256) void prep_tables(
    const float* __restrict__ f0_w2, const float* __restrict__ f0_b2,
    const float* __restrict__ ptab, const float* __restrict__ mtab,
    const float* __restrict__ dur_w2, const float* __restrict__ dur_b2,
    const float* __restrict__ W1, const float* __restrict__ pb1,
    float* __restrict__ wsf) {
  const int r = blockIdx.x, n = threadIdx.x;
  if (r < 64) {  // Wfd row r
    float s = 0.f;
    if (r < 32) {
      for (int j = 0; j < 64; ++j) s = fmaf(f0_w2[r * 64 + j], W1[j * 256 + n], s);
    } else {
      for (int j = 0; j < 64; ++j) s = fmaf(dur_w2[(r - 32) * 64 + j], W1[(256 + j) * 256 + n], s);
    }
    wsf[WFD_OFF / 4 + r * 256 + n] = s;
  } else if (r < 164) {  // Tp row
    const int p = r - 64;
    float s = 0.f;
    for (int j = 0; j < 128; ++j) s = fmaf(ptab[p * 128 + j], W1[(64 + j) * 256 + n], s);
    wsf[TP_OFF / 4 + p * 256 + n] = s;
  } else if (r < 292) {  // Tm row
    const int m = r - 164;
    float s = 0.f;
    for (int j = 0; j < 64; ++j) s = fmaf(mtab[m * 64 + j], W1[(192 + j) * 256 + n], s);
    wsf[TM_OFF / 4 + m * 256 + n] = s;
  } else {  // fused bias
    float s = pb1[n];
    for (int j = 0; j < 64; ++j) {
      s = fmaf(f0_b2[j], W1[j * 256 + n], s);
      s = fmaf(dur_b2[j], W1[(256 + j) * 256 + n], s);
    }
    wsf[BC_OFF / 4 + n] = s;
  }
}

__global__ __launch_bounds__(64) void prep_frags(const float* __restrict__ W2, char* __restrict__ ws) {
  const float* Wfd = (const float*)(ws + WFD_OFF);
  const int t = blockIdx.x;
  const int l = threadIdx.x;
  const int qq = l >> 4, c = l & 15;
  if (t < 64) {  // B1: [Wfd; Wfd] duplicated over K=128 (A is hi/lo split)
    const int kt = t >> 4, nt = t & 15;
    const int col = (nt >> 2) * 64 + c * 4 + (nt & 3);  // permuted column layout
    f16x8 v;
#pragma unroll
    for (int e = 0; e < 8; ++e) {
      const int k = kt * 32 + 4 * qq + (e & 3) + 16 * (e >> 2);
      v[e] = (_Float16)Wfd[(k & 63) * 256 + col];
    }
    *(f16x8*)(ws + B1F_OFF + (unsigned)((kt * 16 + nt) * 64 + l) * 16u) = v;
  } else {  // B2 = proj_w2
    const int t2 = t - 64;
    const int kt = t2 >> 4, nt = t2 & 15;
    const int col = (nt >> 2) * 64 + c * 4 + (nt & 3);  // permuted column layout
    f16x8 v;
#pragma unroll
    for (int e = 0; e < 8; ++e) {
      const int k = kt * 32 + 4 * qq + (e & 3) + 16 * (e >> 2);
      v[e] = (_Float16)W2[k * 256 + col];
    }
    *(f16x8*)(ws + B2F_OFF + (unsigned)((kt * 16 + nt) * 64 + l) * 16u) = v;
  }
}

__global__ __launch_bounds__(256, 2) void cond_enc_main(
    const float* __restrict__ f0g, const int* __restrict__ phone,
    const float* __restrict__ durg, const int* __restrict__ midi,
    const float* __restrict__ f0_w1, const float* __restrict__ f0_b1,
    const float* __restrict__ dur_w1, const float* __restrict__ dur_b1,
    const float* __restrict__ ln_g, const float* __restrict__ ln_b,
    const float* __restrict__ pb2, const char* __restrict__ ws,
    float* __restrict__ out) {
  // LDS: [0,16K) A2 frags (swizzled via afoff); then LN partials [32][12] f32
  __shared__ __align__(16) unsigned char smem[16384 + 1536];
  unsigned char* Afrag = smem;
  float* partials = (float*)(smem + 16384);

  const int tid = threadIdx.x;
  const int l = tid & 63;
  const int wc = tid >> 6;  // wave 0..3 = column group (64 cols each)
  const int q = l >> 4;     // 0..3
  const int c = l & 15;     // 0..15
  const int b = blockIdx.x;

  const float* Tp = (const float*)(ws + TP_OFF);
  const float* Tm = (const float*)(ws + TM_OFF);

  // ---- one coalesced load per lane; rows redistributed via shfl broadcast ----
  const int rl = l & 31;  // row covered by this lane (2x redundant across wave)
  const float xf_all = f0g[b * BM + rl];
  const float xd_all = durg[b * BM + rl];
  const int ph_all = phone[b * BM + rl];
  const int md_all = midi[b * BM + rl];

  // ---- Phase 0: A1 fragments fully in registers ----
  // a = relu(x*w1+b1), hi/lo f16 split. kt0=f0.hi kt1=dur.hi kt2=f0.lo kt3=dur.lo
  f16x8 a1[2][4];
#pragma unroll
  for (int i = 0; i < 2; ++i) {
    const float xf = __shfl(xf_all, i * 16 + c);
    const float xd = __shfl(xd_all, i * 16 + c);
#pragma unroll
    for (int kh = 0; kh < 2; ++kh) {
      f16x8 hi, lo;
#pragma unroll
      for (int e = 0; e < 8; ++e) {
        const int ki = 4 * q + (e & 3) + 16 * (e >> 2);  // 0..31
        const float wv = kh ? dur_w1[ki] : f0_w1[ki];
        const float bv = kh ? dur_b1[ki] : f0_b1[ki];
        const float x = kh ? xd : xf;
        const float a = fmaxf(fmaf(x, wv, bv), 0.f);
        const _Float16 h = (_Float16)a;
        hi[e] = h;
        lo[e] = (_Float16)(a - (float)h);
      }
      a1[i][kh] = hi;
      a1[i][kh + 2] = lo;
    }
  }

  // ---- Phase 1: GEMM1  h = [a_hi|a_lo] @ [Wfd;Wfd]  (K=128) ----
  const f32x4 zero4 = {0.f, 0.f, 0.f, 0.f};
  f32x4 acc[2][4];
#pragma unroll
  for (int i = 0; i < 2; ++i)
#pragma unroll
    for (int j = 0; j < 4; ++j) acc[i][j] = zero4;
  {
    const f16x8* B1p = (const f16x8*)(ws + B1F_OFF);
#pragma unroll
    for (int kt = 0; kt < 4; ++kt) {
      f16x8 b4[4];
#pragma unroll
      for (int j = 0; j < 4; ++j) b4[j] = B1p[(kt * 16 + wc * 4 + j) * 64 + l];
#pragma unroll
      for (int i = 0; i < 2; ++i)
#pragma unroll
        for (int j = 0; j < 4; ++j)
          acc[i][j] = __builtin_amdgcn_mfma_f32_16x16x32_f16(a1[i][kt], b4[j], acc[i][j], 0, 0, 0);
    }
  }

  // ---- Epilogue: += bias + Tp[phone] + Tm[midi] (plain float4 gathers) ----
  // Lane (wc,q,c) holds cols wc*64 + c*4 + {0..3} for rows i*16 + q*4 + r.
  const f32x4 bc4 = *(const f32x4*)((const float*)(ws + BC_OFF) + wc * 64 + c * 4);
  float psum[2][4], psq[2][4];
#pragma unroll
  for (int i = 0; i < 2; ++i) {
#pragma unroll
    for (int r = 0; r < 4; ++r) {
      const int ph = __shfl(ph_all, i * 16 + q * 4 + r);
      const int md = __shfl(md_all, i * 16 + q * 4 + r);
      const f32x4 tp4 = *(const f32x4*)(Tp + ph * 256 + wc * 64 + c * 4);
      const f32x4 tm4 = *(const f32x4*)(Tm + md * 256 + wc * 64 + c * 4);
      float s = 0.f, ss = 0.f;
#pragma unroll
      for (int j = 0; j < 4; ++j) {
        float v = acc[i][j][r] + bc4[j] + tp4[j] + tm4[j];
        acc[i][j][r] = v;
        s += v;
        ss = fmaf(v, v, ss);
      }
      psum[i][r] = s;
      psq[i][r] = ss;
    }
  }
#pragma unroll
  for (int i = 0; i < 2; ++i)
#pragma unroll
    for (int r = 0; r < 4; ++r) {
      float s = psum[i][r], ss = psq[i][r];
#pragma unroll
      for (int m = 1; m < 16; m <<= 1) {  // reduce across the 16 col-lanes
        s += __shfl_xor(s, m, 64);
        ss += __shfl_xor(ss, m, 64);
      }
      psum[i][r] = s;
      psq[i][r] = ss;
    }
  if (c == 0) {
#pragma unroll
    for (int i = 0; i < 2; ++i)
#pragma unroll
      for (int r = 0; r < 4; ++r) {
        const int row = i * 16 + q * 4 + r;
        partials[row * 12 + wc * 2 + 0] = psum[i][r];
        partials[row * 12 + wc * 2 + 1] = psq[i][r];
      }
  }
  __syncthreads();

  // ---- LN (redundant per lane) + ReLU + direct 8B pack into A2 frags ----
  // Lane's 4 consecutive cols form exactly one half-granule of an A2 fragment:
  //   cg = wc*16+c; kt = cg>>3; lane lp = (q*4+r) + 16*(c&3); byte half = (c>>2)&1.
  const f32x4 g4 = *(const f32x4*)(ln_g + wc * 64 + c * 4);
  const f32x4 lb4 = *(const f32x4*)(ln_b + wc * 64 + c * 4);
  const int kt_pk = wc * 2 + (c >> 3);
  const int lp_base = 16 * (c & 3);
  const unsigned hoff = (unsigned)((c >> 2) & 1) * 8u;
#pragma unroll
  for (int i = 0; i < 2; ++i) {
#pragma unroll
    for (int r = 0; r < 4; ++r) {
      const int row = i * 16 + q * 4 + r;
      const f32x4 pa = *(const f32x4*)(partials + row * 12);
      const f32x4 pb = *(const f32x4*)(partials + row * 12 + 4);
      const float s = pa[0] + pa[2] + pb[0] + pb[2];
      const float ss = pa[1] + pa[3] + pb[1] + pb[3];
      const float mu = s * (1.f / 256.f);
      const float var = fmaxf(ss * (1.f / 256.f) - mu * mu, 0.f);
      const float rstd = rsqrtf(var + 1e-5f);
      unsigned short h[4];
#pragma unroll
      for (int j = 0; j < 4; ++j) {
        float v = fmaf((acc[i][j][r] - mu) * rstd, g4[j], lb4[j]);
        v = fmaxf(v, 0.f);
        h[j] = __builtin_bit_cast(unsigned short, (_Float16)v);
      }
      u32x2 pkt;
      pkt[0] = (unsigned)h[0] | ((unsigned)h[1] << 16);
      pkt[1] = (unsigned)h[2] | ((unsigned)h[3] << 16);
      const unsigned X = (unsigned)((kt_pk * 2 + i) * 64 + (q * 4 + r + lp_base));
      *(u32x2*)(Afrag + afoff(X) + hoff) = pkt;
    }
  }
  __syncthreads();

  // ---- Phase 2: GEMM2  out = relu(LN(h)) @ W2 + b2  (K=256), acc reused ----
#pragma unroll
  for (int i = 0; i < 2; ++i)
#pragma unroll
    for (int j = 0; j < 4; ++j) acc[i][j] = zero4;
  {
    const f16x8* B2p = (const f16x8*)(ws + B2F_OFF);
#pragma unroll
    for (int kt = 0; kt < 8; ++kt) {
      f16x8 a4[2], b4[4];
#pragma unroll
      for (int i = 0; i < 2; ++i)
        a4[i] = *(const f16x8*)(Afrag + afoff((unsigned)((kt * 2 + i) * 64 + l)));
#pragma unroll
      for (int j = 0; j < 4; ++j) b4[j] = B2p[(kt * 16 + wc * 4 + j) * 64 + l];
#pragma unroll
      for (int i = 0; i < 2; ++i)
#pragma unroll
        for (int j = 0; j < 4; ++j)
          acc[i][j] = __builtin_amdgcn_mfma_f32_16x16x32_f16(a4[i], b4[j], acc[i][j], 0, 0, 0);
    }
  }
  const f32x4 b24 = *(const f32x4*)(pb2 + wc * 64 + c * 4);
#pragma unroll
  for (int i = 0; i < 2; ++i)
#pragma unroll
    for (int r = 0; r < 4; ++r) {
      const int grow = b * BM + i * 16 + q * 4 + r;
      f32x4 st;
#pragma unroll
      for (int j = 0; j < 4; ++j) st[j] = acc[i][j][r] + b24[j];
      *(f32x4*)(out + grow * 256 + wc * 64 + c * 4) = st;  // float4, 256B bursts
    }
}

extern "C" void kernel_launch(void* const* d_in, const int* in_sizes, int n_in,
                              void* d_out, int out_size, void* d_ws, size_t ws_size,
                              hipStream_t stream) {
  (void)in_sizes; (void)n_in; (void)out_size; (void)ws_size;
  const float* f0 = (const float*)d_in[0];
  const int* phone = (const int*)d_in[1];
  const float* dur = (const float*)d_in[2];
  const int* midi = (const int*)d_in[3];
  const float* f0_w1 = (const float*)d_in[4];
  const float* f0_b1 = (const float*)d_in[5];
  const float* f0_w2 = (const float*)d_in[6];
  const float* f0_b2 = (const float*)d_in[7];
  const float* ptab = (const float*)d_in[8];
  const float* mtab = (const float*)d_in[9];
  const float* dur_w1 = (const float*)d_in[10];
  const float* dur_b1 = (const float*)d_in[11];
  const float* dur_w2 = (const float*)d_in[12];
  const float* dur_b2 = (const float*)d_in[13];
  const float* W1 = (const float*)d_in[14];
  const float* pb1 = (const float*)d_in[15];
  const float* ln_g = (const float*)d_in[16];
  const float* ln_b = (const float*)d_in[17];
  const float* W2 = (const float*)d_in[18];
  const float* pb2 = (const float*)d_in[19];
  char* ws = (char*)d_ws;
  float* out = (float*)d_out;

  prep_tables<<<293, 256, 0, stream>>>(f0_w2, f0_b2, ptab, mtab, dur_w2, dur_b2, W1, pb1, (float*)ws);
  prep_frags<<<192, 64, 0, stream>>>(W2, ws);
  cond_enc_main<<<NBLK, 256, 0, stream>>>(f0, phone, dur, midi, f0_w1, f0_b1, dur_w1, dur_b1,
                                          ln_g, ln_b, pb2, ws, out);
}

// Round 6
// 42.298 us; speedup vs baseline: 1.2585x; 1.0830x over previous
//
#include <hip/hip_runtime.h>

typedef _Float16 f16x8 __attribute__((ext_vector_type(8)));
typedef float f32x4 __attribute__((ext_vector_type(4)));
typedef unsigned int u32x2 __attribute__((ext_vector_type(2)));

#define MROWS 65536
#define BM 64
#define NBLK (MROWS / BM)  // 1024

// ---- d_ws byte offsets ----
#define B1F_OFF 0u       // GEMM1 B frags: [4kt][16nt][64lane][8] f16 = 65536 B
#define B2F_OFF 65536u   // GEMM2 B frags: [8kt][16nt][64lane][8] f16 = 131072 B
#define TP_OFF 196608u   // phone_table @ W1[64:192]: [100][256] f32
#define TM_OFF 299008u   // midi_table @ W1[192:256]: [128][256] f32
#define BC_OFF 430080u   // fused bias: [256] f32
#define WFD_OFF 431104u  // fused f0/dur weights: [64][256] f32
// total 496640 B

// Fragment k-slot mapping (all A and B fragments):
//   k = kt*32 + 4*(lane>>4) + (e&3) + 16*(e>>2)
// B fragments use a PERMUTED column layout: tile nt, lane c holds logical
// column (nt>>2)*64 + c*4 + (nt&3). In-wave (nt = wc*4 + j) each lane's four
// j-values are 4 CONSECUTIVE logical columns wc*64 + c*4 + {0..3}: table reads,
// LN params, bias and output stores are plain float4; the LN->GEMM2 repack is
// a pure per-lane 8B LDS write (no shuffles).
// C/D: col_tile = lane&15 (permuted as above); row = (lane>>4)*4 + reg.

// LDS A-frag swizzle: 16B-granule bijection, XORs addr bits [4:6] with X bits [3:5].
__device__ __forceinline__ unsigned afoff(unsigned X) {
  return (X * 16u) ^ ((X & 0x38u) << 1);
}

__global__ __launch_bounds__(256) void prep_tables(
    const float* __restrict__ f0_w2, const float* __restrict__ f0_b2,
    const float* __restrict__ ptab, const float* __restrict__ mtab,
    const float* __restrict__ dur_w2, const float* __restrict__ dur_b2,
    const float* __restrict__ W1, const float* __restrict__ pb1,
    float* __restrict__ wsf) {
  const int r = blockIdx.x, n = threadIdx.x;
  if (r < 64) {  // Wfd row r
    float s = 0.f;
    if (r < 32) {
      for (int j = 0; j < 64; ++j) s = fmaf(f0_w2[r * 64 + j], W1[j * 256 + n], s);
    } else {
      for (int j = 0; j < 64; ++j) s = fmaf(dur_w2[(r - 32) * 64 + j], W1[(256 + j) * 256 + n], s);
    }
    wsf[WFD_OFF / 4 + r * 256 + n] = s;
  } else if (r < 164) {  // Tp row
    const int p = r - 64;
    float s = 0.f;
    for (int j = 0; j < 128; ++j) s = fmaf(ptab[p * 128 + j], W1[(64 + j) * 256 + n], s);
    wsf[TP_OFF / 4 + p * 256 + n] = s;
  } else if (r < 292) {  // Tm row
    const int m = r - 164;
    float s = 0.f;
    for (int j = 0; j < 64; ++j) s = fmaf(mtab[m * 64 + j], W1[(192 + j) * 256 + n], s);
    wsf[TM_OFF / 4 + m * 256 + n] = s;
  } else {  // fused bias
    float s = pb1[n];
    for (int j = 0; j < 64; ++j) {
      s = fmaf(f0_b2[j], W1[j * 256 + n], s);
      s = fmaf(dur_b2[j], W1[(256 + j) * 256 + n], s);
    }
    wsf[BC_OFF / 4 + n] = s;
  }
}

__global__ __launch_bounds__(64) void prep_frags(const float* __restrict__ W2, char* __restrict__ ws) {
  const float* Wfd = (const float*)(ws + WFD_OFF);
  const int t = blockIdx.x;
  const int l = threadIdx.x;
  const int qq = l >> 4, c = l & 15;
  if (t < 64) {  // B1: [Wfd; Wfd] duplicated over K=128 (A is hi/lo split)
    const int kt = t >> 4, nt = t & 15;
    const int col = (nt >> 2) * 64 + c * 4 + (nt & 3);  // permuted column layout
    f16x8 v;
#pragma unroll
    for (int e = 0; e < 8; ++e) {
      const int k = kt * 32 + 4 * qq + (e & 3) + 16 * (e >> 2);
      v[e] = (_Float16)Wfd[(k & 63) * 256 + col];
    }
    *(f16x8*)(ws + B1F_OFF + (unsigned)((kt * 16 + nt) * 64 + l) * 16u) = v;
  } else {  // B2 = proj_w2
    const int t2 = t - 64;
    const int kt = t2 >> 4, nt = t2 & 15;
    const int col = (nt >> 2) * 64 + c * 4 + (nt & 3);  // permuted column layout
    f16x8 v;
#pragma unroll
    for (int e = 0; e < 8; ++e) {
      const int k = kt * 32 + 4 * qq + (e & 3) + 16 * (e >> 2);
      v[e] = (_Float16)W2[k * 256 + col];
    }
    *(f16x8*)(ws + B2F_OFF + (unsigned)((kt * 16 + nt) * 64 + l) * 16u) = v;
  }
}

__global__ __launch_bounds__(256, 2) void cond_enc_main(
    const float* __restrict__ f0g, const int* __restrict__ phone,
    const float* __restrict__ durg, const int* __restrict__ midi,
    const float* __restrict__ f0_w1, const float* __restrict__ f0_b1,
    const float* __restrict__ dur_w1, const float* __restrict__ dur_b1,
    const float* __restrict__ ln_g, const float* __restrict__ ln_b,
    const float* __restrict__ pb2, const char* __restrict__ ws,
    float* __restrict__ out) {
  // LDS: [0,32K) A2 frags (swizzled via afoff); then LN partials [64][12] f32
  __shared__ __align__(16) unsigned char smem[32768 + 3072];
  unsigned char* Afrag = smem;
  float* partials = (float*)(smem + 32768);

  const int tid = threadIdx.x;
  const int l = tid & 63;
  const int wc = tid >> 6;  // wave 0..3 = column group (64 cols each)
  const int q = l >> 4;     // 0..3
  const int c = l & 15;     // 0..15
  const int b = blockIdx.x;

  const float* Tp = (const float*)(ws + TP_OFF);
  const float* Tm = (const float*)(ws + TM_OFF);

  // ---- one coalesced load per lane (lane l covers row l of the 64-row tile) ----
  const float xf_all = f0g[b * BM + l];
  const float xd_all = durg[b * BM + l];
  const int ph_all = phone[b * BM + l];
  const int md_all = midi[b * BM + l];

  // ---- Phase 1: GEMM1  h = [a_hi|a_lo] @ [Wfd;Wfd]  (K=128), two row-halves ----
  // a = relu(x*w1+b1), hi/lo f16 split. kt0=f0.hi kt1=dur.hi kt2=f0.lo kt3=dur.lo
  // a1 is recomputed per half to cap VGPR pressure (~32 regs live, not 64).
  // Second half's B1 re-reads hit L1 (16KB/wave slice).
  const f32x4 zero4 = {0.f, 0.f, 0.f, 0.f};
  f32x4 acc[4][4];
#pragma unroll
  for (int i = 0; i < 4; ++i)
#pragma unroll
    for (int j = 0; j < 4; ++j) acc[i][j] = zero4;
  {
    const f16x8* B1p = (const f16x8*)(ws + B1F_OFF);
#pragma unroll
    for (int h = 0; h < 2; ++h) {
      f16x8 a1[2][4];
#pragma unroll
      for (int ii = 0; ii < 2; ++ii) {
        const int i = h * 2 + ii;
        const float xf = __shfl(xf_all, i * 16 + c);
        const float xd = __shfl(xd_all, i * 16 + c);
#pragma unroll
        for (int kh = 0; kh < 2; ++kh) {
          f16x8 hi, lo;
#pragma unroll
          for (int e = 0; e < 8; ++e) {
            const int ki = 4 * q + (e & 3) + 16 * (e >> 2);  // 0..31
            const float wv = kh ? dur_w1[ki] : f0_w1[ki];
            const float bv = kh ? dur_b1[ki] : f0_b1[ki];
            const float x = kh ? xd : xf;
            const float a = fmaxf(fmaf(x, wv, bv), 0.f);
            const _Float16 hh = (_Float16)a;
            hi[e] = hh;
            lo[e] = (_Float16)(a - (float)hh);
          }
          a1[ii][kh] = hi;
          a1[ii][kh + 2] = lo;
        }
      }
#pragma unroll
      for (int kt = 0; kt < 4; ++kt) {
        f16x8 b4[4];
#pragma unroll
        for (int j = 0; j < 4; ++j) b4[j] = B1p[(kt * 16 + wc * 4 + j) * 64 + l];
#pragma unroll
        for (int ii = 0; ii < 2; ++ii)
#pragma unroll
          for (int j = 0; j < 4; ++j)
            acc[h * 2 + ii][j] =
                __builtin_amdgcn_mfma_f32_16x16x32_f16(a1[ii][kt], b4[j], acc[h * 2 + ii][j], 0, 0, 0);
      }
    }
  }

  // ---- Epilogue: += bias + Tp[phone] + Tm[midi] (plain float4 gathers) ----
  // Lane (wc,q,c) holds cols wc*64 + c*4 + {0..3} for rows i*16 + q*4 + r.
  const f32x4 bc4 = *(const f32x4*)((const float*)(ws + BC_OFF) + wc * 64 + c * 4);
  float psum[4][4], psq[4][4];
#pragma unroll
  for (int i = 0; i < 4; ++i) {
#pragma unroll
    for (int r = 0; r < 4; ++r) {
      const int ph = __shfl(ph_all, i * 16 + q * 4 + r);
      const int md = __shfl(md_all, i * 16 + q * 4 + r);
      const f32x4 tp4 = *(const f32x4*)(Tp + ph * 256 + wc * 64 + c * 4);
      const f32x4 tm4 = *(const f32x4*)(Tm + md * 256 + wc * 64 + c * 4);
      float s = 0.f, ss = 0.f;
#pragma unroll
      for (int j = 0; j < 4; ++j) {
        float v = acc[i][j][r] + bc4[j] + tp4[j] + tm4[j];
        acc[i][j][r] = v;
        s += v;
        ss = fmaf(v, v, ss);
      }
      psum[i][r] = s;
      psq[i][r] = ss;
    }
  }
#pragma unroll
  for (int i = 0; i < 4; ++i)
#pragma unroll
    for (int r = 0; r < 4; ++r) {
      float s = psum[i][r], ss = psq[i][r];
#pragma unroll
      for (int m = 1; m < 16; m <<= 1) {  // reduce across the 16 col-lanes
        s += __shfl_xor(s, m, 64);
        ss += __shfl_xor(ss, m, 64);
      }
      psum[i][r] = s;
      psq[i][r] = ss;
    }
  if (c == 0) {
#pragma unroll
    for (int i = 0; i < 4; ++i)
#pragma unroll
      for (int r = 0; r < 4; ++r) {
        const int row = i * 16 + q * 4 + r;
        partials[row * 12 + wc * 2 + 0] = psum[i][r];
        partials[row * 12 + wc * 2 + 1] = psq[i][r];
      }
  }
  __syncthreads();

  // ---- LN (redundant per lane) + ReLU + direct 8B pack into A2 frags ----
  // Lane's 4 consecutive cols = one half-granule of an A2 fragment:
  //   kt = wc*2 + (c>>3); lane lp = (q*4+r) + 16*(c&3); byte half = (c>>2)&1.
  const f32x4 g4 = *(const f32x4*)(ln_g + wc * 64 + c * 4);
  const f32x4 lb4 = *(const f32x4*)(ln_b + wc * 64 + c * 4);
  const int kt_pk = wc * 2 + (c >> 3);
  const int lp_base = 16 * (c & 3);
  const unsigned hoff = (unsigned)((c >> 2) & 1) * 8u;
#pragma unroll
  for (int i = 0; i < 4; ++i) {
#pragma unroll
    for (int r = 0; r < 4; ++r) {
      const int row = i * 16 + q * 4 + r;
      const f32x4 pa = *(const f32x4*)(partials + row * 12);
      const f32x4 pb = *(const f32x4*)(partials + row * 12 + 4);
      const float s = pa[0] + pa[2] + pb[0] + pb[2];
      const float ss = pa[1] + pa[3] + pb[1] + pb[3];
      const float mu = s * (1.f / 256.f);
      const float var = fmaxf(ss * (1.f / 256.f) - mu * mu, 0.f);
      const float rstd = rsqrtf(var + 1e-5f);
      unsigned short hw[4];
#pragma unroll
      for (int j = 0; j < 4; ++j) {
        float v = fmaf((acc[i][j][r] - mu) * rstd, g4[j], lb4[j]);
        v = fmaxf(v, 0.f);
        hw[j] = __builtin_bit_cast(unsigned short, (_Float16)v);
      }
      u32x2 pkt;
      pkt[0] = (unsigned)hw[0] | ((unsigned)hw[1] << 16);
      pkt[1] = (unsigned)hw[2] | ((unsigned)hw[3] << 16);
      const unsigned X = (unsigned)((kt_pk * 4 + i) * 64 + (q * 4 + r + lp_base));
      *(u32x2*)(Afrag + afoff(X) + hoff) = pkt;
    }
  }
  __syncthreads();

  // ---- Phase 2: GEMM2  out = relu(LN(h)) @ W2 + b2  (K=256), acc reused ----
#pragma unroll
  for (int i = 0; i < 4; ++i)
#pragma unroll
    for (int j = 0; j < 4; ++j) acc[i][j] = zero4;
  {
    const f16x8* B2p = (const f16x8*)(ws + B2F_OFF);
#pragma unroll
    for (int kt = 0; kt < 8; ++kt) {
      f16x8 a4[4], b4[4];
#pragma unroll
      for (int i = 0; i < 4; ++i)
        a4[i] = *(const f16x8*)(Afrag + afoff((unsigned)((kt * 4 + i) * 64 + l)));
#pragma unroll
      for (int j = 0; j < 4; ++j) b4[j] = B2p[(kt * 16 + wc * 4 + j) * 64 + l];
#pragma unroll
      for (int i = 0; i < 4; ++i)
#pragma unroll
        for (int j = 0; j < 4; ++j)
          acc[i][j] = __builtin_amdgcn_mfma_f32_16x16x32_f16(a4[i], b4[j], acc[i][j], 0, 0, 0);
    }
  }
  const f32x4 b24 = *(const f32x4*)(pb2 + wc * 64 + c * 4);
#pragma unroll
  for (int i = 0; i < 4; ++i)
#pragma unroll
    for (int r = 0; r < 4; ++r) {
      const int grow = b * BM + i * 16 + q * 4 + r;
      f32x4 st;
#pragma unroll
      for (int j = 0; j < 4; ++j) st[j] = acc[i][j][r] + b24[j];
      // nontemporal: keep the 65.5MB write stream out of L2/L3 so it doesn't
      // evict the shared B-frag / gather tables.
      __builtin_nontemporal_store(st, (f32x4*)(out + grow * 256 + wc * 64 + c * 4));
    }
}

extern "C" void kernel_launch(void* const* d_in, const int* in_sizes, int n_in,
                              void* d_out, int out_size, void* d_ws, size_t ws_size,
                              hipStream_t stream) {
  (void)in_sizes; (void)n_in; (void)out_size; (void)ws_size;
  const float* f0 = (const float*)d_in[0];
  const int* phone = (const int*)d_in[1];
  const float* dur = (const float*)d_in[2];
  const int* midi = (const int*)d_in[3];
  const float* f0_w1 = (const float*)d_in[4];
  const float* f0_b1 = (const float*)d_in[5];
  const float* f0_w2 = (const float*)d_in[6];
  const float* f0_b2 = (const float*)d_in[7];
  const float* ptab = (const float*)d_in[8];
  const float* mtab = (const float*)d_in[9];
  const float* dur_w1 = (const float*)d_in[10];
  const float* dur_b1 = (const float*)d_in[11];
  const float* dur_w2 = (const float*)d_in[12];
  const float* dur_b2 = (const float*)d_in[13];
  const float* W1 = (const float*)d_in[14];
  const float* pb1 = (const float*)d_in[15];
  const float* ln_g = (const float*)d_in[16];
  const float* ln_b = (const float*)d_in[17];
  const float* W2 = (const float*)d_in[18];
  const float* pb2 = (const float*)d_in[19];
  char* ws = (char*)d_ws;
  float* out = (float*)d_out;

  prep_tables<<<293, 256, 0, stream>>>(f0_w2, f0_b2, ptab, mtab, dur_w2, dur_b2, W1, pb1, (float*)ws);
  prep_frags<<<192, 64, 0, stream>>>(W2, ws);
  cond_enc_main<<<NBLK, 256, 0, stream>>>(f0, phone, dur, midi, f0_w1, f0_b1, dur_w1, dur_b1,
                                          ln_g, ln_b, pb2, ws, out);
}